// Round 16
// baseline (510.620 us; speedup 1.0000x reference)
//
#include <hip/hip_runtime.h>
#include <cstdint>
#include <cstddef>

typedef __bf16 bf16x8 __attribute__((ext_vector_type(8)));
typedef float f32x4 __attribute__((ext_vector_type(4)));

// ---------------- ws layout ----------------
// bytes [0, 2359296): wt bf16 [16][2][9][64(oc)][64(ic)]
// float offset 589824: xp [16][64]; 590848: gates [16][16]; 591104: pool partials [16][64][64]
// bytes [4MB, 4MB+33554432): xt bf16 [16][16384(pixel)][64(ch)]  (NHWC)
#define XP_OFF_F    589824
#define GATES_OFF_F 590848
#define PART_OFF_F  591104
#define XT_OFF_B    (4u<<20)

// LDS xs geometry: 8 chunks x 404 pixels x 8 ch (bf16). chunk stride 3232 ushorts.
#define XCH 3232

__device__ __forceinline__ float bf2f(unsigned short h){
  return __uint_as_float(((uint32_t)h)<<16);
}
__device__ __forceinline__ unsigned short f2bf(float f){
  uint32_t u = __float_as_uint(f);
  u = u + 0x7fffu + ((u>>16)&1u);   // RNE
  return (unsigned short)(u>>16);
}
__device__ __forceinline__ uint32_t pk_bf16(float lo, float hi){
  uint32_t r;
  asm("v_cvt_pk_bf16_f32 %0, %1, %2" : "=v"(r) : "v"(lo), "v"(hi));
  return r;
}
// fast exact-GELU: erf via A&S 7.1.26 (|eps|<=1.5e-7, far below bf16 rounding)
__device__ __forceinline__ float gelu_exact(float x){
  float s = x * 0.70710678118654752440f;
  float a = __builtin_fabsf(s);
  float t = __builtin_amdgcn_rcpf(__builtin_fmaf(0.3275911f, a, 1.0f));
  float p = __builtin_fmaf(1.061405429f, t, -1.453152027f);
  p = __builtin_fmaf(p, t, 1.421413741f);
  p = __builtin_fmaf(p, t, -0.284496736f);
  p = __builtin_fmaf(p, t, 0.254829592f);
  p = p * t;
  float e = __expf(-a*a);
  float erfa = __builtin_fmaf(-p, e, 1.0f);
  float erfv = (s < 0.f) ? -erfa : erfa;
  return 0.5f * x * (1.0f + erfv);
}

// ---------------- weight transpose+cast: W[e][oc][ic][3][3] -> wt[e][c][tap][oc][ic] bf16
__global__ __launch_bounds__(256) void wtrans_kernel(const float* __restrict__ W1,
                                                     const float* __restrict__ W2,
                                                     unsigned short* __restrict__ wt){
  int idx = blockIdx.x*256 + threadIdx.x;      // 0 .. 1,179,647
  int ic  = idx & 63;
  int oc  = (idx>>6) & 63;
  int tap = (idx>>12) % 9;
  int ec  = idx / 36864;                       // e*2 + c
  int e = ec >> 1, c = ec & 1;
  const float* src = c ? W2 : W1;
  wt[idx] = f2bf(src[((e*64 + oc)*64 + ic)*9 + tap]);
}

// ---------------- fused: x NCHW fp32 -> NHWC bf16  +  pool partial sums
__global__ __launch_bounds__(256) void xpose_pool_kernel(const float* __restrict__ x,
                                                         unsigned short* __restrict__ xt,
                                                         float* __restrict__ wsf){
  int b = blockIdx.y;
  int tid = threadIdx.x;
  int p = blockIdx.x*256 + tid;                // 0..16383
  const float* xb = x + (size_t)b*1048576;
  __shared__ float part[64][4];
  const int lane = tid & 63, wid = tid >> 6;
  unsigned short v[64];
  #pragma unroll
  for (int c = 0; c < 64; ++c){
    float f = xb[c*16384 + p];
    v[c] = f2bf(f);
    #pragma unroll
    for (int off = 32; off; off >>= 1) f += __shfl_down(f, off);
    if (lane == 0) part[c][wid] = f;
  }
  uint4* dst = reinterpret_cast<uint4*>(xt + (size_t)b*1048576 + (size_t)p*64);
  const uint4* src = reinterpret_cast<const uint4*>(v);
  #pragma unroll
  for (int i = 0; i < 8; ++i) dst[i] = src[i];
  __syncthreads();
  if (tid < 64)
    wsf[PART_OFF_F + (b*64 + blockIdx.x)*64 + tid] =
      part[tid][0] + part[tid][1] + part[tid][2] + part[tid][3];
}

// ---------------- deterministic partial reduce -> xp[b][c]
__global__ __launch_bounds__(256) void pool_reduce_kernel(float* __restrict__ wsf){
  int i = blockIdx.x*256 + threadIdx.x;        // 0..1023 = b*64 + c
  int b = i >> 6, c = i & 63;
  float s = 0.f;
  for (int cx = 0; cx < 64; ++cx)
    s += wsf[PART_OFF_F + (b*64 + cx)*64 + c];
  wsf[XP_OFF_F + i] = s * (1.0f/16384.0f);
}

// ---------------- gating: logits -> softmax -> top2 -> gates + aux
__global__ __launch_bounds__(256) void gate_kernel(const float* __restrict__ tf,
    const float* __restrict__ Wx, const float* __restrict__ Wt,
    const float* __restrict__ bg, float* __restrict__ wsf,
    float* __restrict__ out_aux){
  __shared__ float lg[16][16];
  __shared__ float gsh[16][16];
  int tid = threadIdx.x;
  int b = tid >> 4, e = tid & 15;
  const float* xp = wsf + XP_OFF_F;
  float acc = bg[e];
  for (int c = 0; c < 64;  ++c) acc += xp[b*64 + c] * Wx[c*16 + e];
  for (int d = 0; d < 512; ++d) acc += tf[b*512 + d] * Wt[d*16 + e];
  lg[b][e] = acc;
  __syncthreads();
  if (tid < 16) {
    int bb = tid;
    float m = -1e30f;
    for (int j = 0; j < 16; ++j) m = fmaxf(m, lg[bb][j]);
    float pr[16]; float s = 0.f;
    for (int j = 0; j < 16; ++j){ pr[j] = expf(lg[bb][j] - m); s += pr[j]; }
    float invs = 1.f/s;
    for (int j = 0; j < 16; ++j) pr[j] *= invs;
    int i1 = 0; float v1 = pr[0];
    for (int j = 1; j < 16; ++j) if (pr[j] > v1){ v1 = pr[j]; i1 = j; }
    float v2 = -1.f; int i2 = 0;
    for (int j = 0; j < 16; ++j) if (j != i1 && pr[j] > v2){ v2 = pr[j]; i2 = j; }
    float inv = 1.f/(v1 + v2);
    for (int j = 0; j < 16; ++j) gsh[bb][j] = 0.f;
    gsh[bb][i1] = v1*inv;
    gsh[bb][i2] = v2*inv;
    for (int j = 0; j < 16; ++j) wsf[GATES_OFF_F + bb*16 + j] = gsh[bb][j];
  }
  __syncthreads();
  if (tid == 0){
    float imp[16]; float mean = 0.f;
    for (int j = 0; j < 16; ++j){
      float t = 0.f;
      for (int bb = 0; bb < 16; ++bb) t += gsh[bb][j];
      imp[j] = t; mean += t;
    }
    mean *= (1.f/16.f);
    float m2 = 0.f;
    for (int j = 0; j < 16; ++j){ float d = imp[j] - mean; m2 += d*d; }
    float var = m2 * (1.f/16.f);
    out_aux[0] = var / (mean*mean + 1e-10f);
  }
}

// ---------------- merged MoE kernel: 512 threads, swapped-operand MFMA.
// conv1: async weight DMA (slabs 0..8, counted vmcnt protocol, 9 barrier phases).
// conv2: BARRIER-FREE — weights direct from global with explicit 2-deep
//        register ping-pong prefetch; h1 (xs) is stable, compiler schedules.
// Per sample, blockIdx.x layout:
//   [0,384):     TYPE0, e = 3*(i/64),          tile = i%64   (8x8 tiles, S=128)
//   [384,1664):  TYPE1, e = 3*((i-384)/256)+1, tile = (i-384)%256 (16x16, S=256)
//   [1664,1744): TYPE2, e = 3*((i-1664)/16)+2, tile = (i-1664)%16 (4x4, S=64)
// conv as tap-decomposed GEMM: D[oc][px] = mfma(A=W[oc][ic], B=P[px][ic]).
__global__ __launch_bounds__(512, 4) void moe_kernel(
    const unsigned short* __restrict__ xt, const unsigned short* __restrict__ wt,
    const float* __restrict__ wsf,
    const float* __restrict__ b1, const float* __restrict__ b2,
    float* __restrict__ out)
{
  __shared__ unsigned short xs[8*XCH];     // 51.7 KB: [chunk][404 px][8 ch]; halo, then h1
  __shared__ unsigned short wbuf[3][4096]; // 24 KB: 3 x [64 oc][64 ic] conv1 tap slabs
  const int b = blockIdx.y;
  const int i = blockIdx.x;
  int e, tile, type, S, TILES;
  if (i < 384)       { type = 0; e = 3*(i>>6);            tile = i & 63;        S = 128; TILES = 8;  }
  else if (i < 1664) { type = 1; e = 3*((i-384)>>8) + 1;  tile = (i-384) & 255; S = 256; TILES = 16; }
  else               { type = 2; e = 3*((i-1664)>>4) + 2; tile = (i-1664) & 15; S = 64;  TILES = 4;  }

  const float g = wsf[GATES_OFF_F + b*16 + e];
  if (g == 0.0f) return;                 // inactive expert for this sample

  const int ty0 = (tile / TILES)*16;
  const int tx0 = (tile % TILES)*16;
  const int tid  = threadIdx.x;
  const int lane = tid & 63;
  const int wid  = tid >> 6;           // 0..7
  const int lr   = lane & 15;
  const int k16  = lane >> 4;          // 0..3
  const int l4   = k16 * 4;            // C/D row sub-offset

  const unsigned short* wt1 = wt + (size_t)(e*2 + 0)*36864;
  const unsigned short* wt2 = wt + (size_t)(e*2 + 1)*36864;
  const unsigned short* xtb = xt + (size_t)b*1048576;   // [pixel][64]

  // ---- preload conv1 bias into registers (no stray vmem loads inside the
  //      conv1 loop: the vmcnt protocol counts only weight DMAs)
  float b1v[4][4];
  #pragma unroll
  for (int nt = 0; nt < 4; ++nt){
    float4 v = *reinterpret_cast<const float4*>(b1 + e*64 + nt*16 + l4);
    b1v[nt][0] = v.x; b1v[nt][1] = v.y; b1v[nt][2] = v.z; b1v[nt][3] = v.w;
  }

  // ---- async conv1 weight DMA: slab j (8KB, tap j) -> wbuf[j%3], j in [0,9)
  const int woc = tid >> 3, wch = tid & 7;
  const int wsc = wch ^ (woc & 7);
  auto dma_slab = [&](int j){
    if (j < 9){
      const unsigned short* gsrc = wt1 + j*4096 + woc*64 + wsc*8;
      __builtin_amdgcn_global_load_lds(
          (const __attribute__((address_space(1))) void*)gsrc,
          (__attribute__((address_space(3))) void*)(&wbuf[j % 3][wid << 9]),
          16, 0, 0);
    }
  };
  const int wb0 = lr*64 + (((0*4+k16) ^ (lr&7))*8);
  const int wb1 = lr*64 + (((1*4+k16) ^ (lr&7))*8);

  dma_slab(0); dma_slab(1);    // in flight during xs staging

  // ---- stage 20x20x64 input halo -> xs[chunk][p][8]; 400 px, 1 per thread
  if (tid < 400){
    int p = tid;
    int hy = p/20, hx = p - hy*20;
    int sy = ty0 - 2 + hy, sx = tx0 - 2 + hx;      // conv-res coords
    bool valid = (sy >= 0) & (sy < S) & (sx < S) & (sx >= 0);
    if (!valid){
      uint4 z = make_uint4(0,0,0,0);
      #pragma unroll
      for (int c = 0; c < 8; ++c)
        *reinterpret_cast<uint4*>(&xs[c*XCH + p*8]) = z;
    } else if (type == 0){
      const uint4* src = reinterpret_cast<const uint4*>(xtb + ((size_t)(sy*128 + sx))*64);
      #pragma unroll
      for (int c = 0; c < 8; ++c)
        *reinterpret_cast<uint4*>(&xs[c*XCH + p*8]) = src[c];
    } else if (type == 1){
      const uint4* src = reinterpret_cast<const uint4*>(xtb + ((size_t)((sy>>1)*128 + (sx>>1)))*64);
      #pragma unroll
      for (int c = 0; c < 8; ++c)
        *reinterpret_cast<uint4*>(&xs[c*XCH + p*8]) = src[c];
    } else {
      // 2x2 maxpool on bf16 (exact: RNE is monotone)
      const uint4* q00 = reinterpret_cast<const uint4*>(xtb + ((size_t)(sy*256 + sx*2))*64);
      const uint4* q01 = q00 + 8;
      const uint4* q10 = q00 + 128*8;
      const uint4* q11 = q10 + 8;
      #pragma unroll
      for (int c = 0; c < 8; ++c){
        union { unsigned short u[8]; uint4 v; } a0,a1,a2,a3,o;
        a0.v = q00[c]; a1.v = q01[c]; a2.v = q10[c]; a3.v = q11[c];
        #pragma unroll
        for (int j = 0; j < 8; ++j){
          float m = fmaxf(fmaxf(bf2f(a0.u[j]), bf2f(a1.u[j])),
                          fmaxf(bf2f(a2.u[j]), bf2f(a3.u[j])));
          o.u[j] = f2bf(m);
        }
        *reinterpret_cast<uint4*>(&xs[c*XCH + p*8]) = o.v;
      }
    }
  }

  // conv1 B-frag pixel bases (halo coords): 24 frags of 16 over 324 h1 px (clamped)
  int pb1[3];
  #pragma unroll
  for (int ii = 0; ii < 3; ++ii){
    int q = (wid*3 + ii)*16 + lr;
    q = q > 323 ? 323 : q;
    pb1[ii] = ((q/18)*20 + (q%18))*8 + k16*XCH;    // +kf*4*XCH, +poff*8 as imm
  }

  asm volatile("s_waitcnt lgkmcnt(0) vmcnt(1)" ::: "memory");
  __builtin_amdgcn_s_barrier();

  // ---- conv1: 9 tap-phases; slab t resident, slab t+1 arriving, issue t+2
  f32x4 acc1[3][4];
  #pragma unroll
  for (int ii = 0; ii < 3; ++ii)
    #pragma unroll
    for (int nt = 0; nt < 4; ++nt)
      acc1[ii][nt] = (f32x4){0.f,0.f,0.f,0.f};

  #pragma unroll
  for (int t = 0; t < 9; ++t){
    dma_slab(t+2);                      // no-op for t >= 7 (j clamped at 9)
    const unsigned short* wb = &wbuf[t % 3][0];
    const int poff = ((t/3)*20 + (t%3))*8;
    #pragma unroll
    for (int kf = 0; kf < 2; ++kf){
      bf16x8 Wf[4], Pf[3];
      #pragma unroll
      for (int nt = 0; nt < 4; ++nt)
        Wf[nt] = *reinterpret_cast<const bf16x8*>(wb + (kf ? wb1 : wb0) + nt*1024);
      #pragma unroll
      for (int ii = 0; ii < 3; ++ii)
        Pf[ii] = *reinterpret_cast<const bf16x8*>(&xs[pb1[ii] + kf*4*XCH + poff]);
      #pragma unroll
      for (int ii = 0; ii < 3; ++ii)
        #pragma unroll
        for (int nt = 0; nt < 4; ++nt)
          acc1[ii][nt] = __builtin_amdgcn_mfma_f32_16x16x32_bf16(Wf[nt], Pf[ii], acc1[ii][nt], 0, 0, 0);
    }
    // counted drain: need slab t+1 resident for next phase.
    if (t < 7){
      asm volatile("s_waitcnt vmcnt(1)" ::: "memory");
      __builtin_amdgcn_s_barrier();
    } else if (t == 7){
      asm volatile("s_waitcnt vmcnt(0)" ::: "memory");   // last DMA (slab 8)
      __builtin_amdgcn_s_barrier();
    } else {
      __builtin_amdgcn_s_barrier();     // t==8: protect xs before h1 overwrite
    }
  }

  // ---- bias + GELU -> h1 in xs[chunk][q][8] (zero outside image: ref zero-pads h1)
  #pragma unroll
  for (int ii = 0; ii < 3; ++ii){
    int q = (wid*3 + ii)*16 + lr;
    if (q < 324){
      int qy = q/18, qx = q - qy*18;
      int gy = ty0 - 1 + qy, gx = tx0 - 1 + qx;
      bool in_img = (gy >= 0) & (gy < S) & (gx >= 0) & (gx < S);
      int hb = (l4 >> 3)*XCH + q*8 + (l4 & 4);     // + nt*2*XCH as imm
      #pragma unroll
      for (int nt = 0; nt < 4; ++nt){
        float v0 = in_img ? gelu_exact(acc1[ii][nt][0] + b1v[nt][0]) : 0.f;
        float v1 = in_img ? gelu_exact(acc1[ii][nt][1] + b1v[nt][1]) : 0.f;
        float v2 = in_img ? gelu_exact(acc1[ii][nt][2] + b1v[nt][2]) : 0.f;
        float v3 = in_img ? gelu_exact(acc1[ii][nt][3] + b1v[nt][3]) : 0.f;
        uint2 w;
        w.x = pk_bf16(v0, v1);
        w.y = pk_bf16(v2, v3);
        *reinterpret_cast<uint2*>(&xs[nt*2*XCH + hb]) = w;
      }
    }
  }

  asm volatile("s_waitcnt lgkmcnt(0)" ::: "memory");
  __builtin_amdgcn_s_barrier();

  // conv2 B-frag pixel bases
  int pb2[2];
  #pragma unroll
  for (int ii = 0; ii < 2; ++ii)
    pb2[ii] = ((wid*2 + ii)*18 + lr)*8 + k16*XCH;

  // ---- conv2: BARRIER-FREE. Weights direct from global (L2-hot), 2-deep
  // register ping-pong; h1 (xs) is stable so P reads are freely schedulable.
  f32x4 acc2[2][4];
  #pragma unroll
  for (int ii = 0; ii < 2; ++ii)
    #pragma unroll
    for (int nt = 0; nt < 4; ++nt)
      acc2[ii][nt] = (f32x4){0.f,0.f,0.f,0.f};

  {
    const unsigned short* w2base = wt2 + lr*64 + k16*8;  // + tap*4096 + kf*32 + nt*1024
    bf16x8 W2f[2][4];
    #pragma unroll
    for (int nt = 0; nt < 4; ++nt)
      W2f[0][nt] = *reinterpret_cast<const bf16x8*>(w2base + nt*1024);   // s=0: tap0,kf0
    #pragma unroll
    for (int s = 0; s < 18; ++s){
      const int cur = s & 1, nxt = cur ^ 1;
      const int tap = s >> 1, kf = s & 1;
      if (s < 17){
        const int tn = (s+1) >> 1, kfn = (s+1) & 1;
        #pragma unroll
        for (int nt = 0; nt < 4; ++nt)
          W2f[nxt][nt] = *reinterpret_cast<const bf16x8*>(w2base + tn*4096 + kfn*32 + nt*1024);
      }
      const int poff = ((tap/3)*18 + (tap%3))*8;
      bf16x8 Pf[2];
      #pragma unroll
      for (int ii = 0; ii < 2; ++ii)
        Pf[ii] = *reinterpret_cast<const bf16x8*>(&xs[pb2[ii] + kf*4*XCH + poff]);
      #pragma unroll
      for (int ii = 0; ii < 2; ++ii)
        #pragma unroll
        for (int nt = 0; nt < 4; ++nt)
          acc2[ii][nt] = __builtin_amdgcn_mfma_f32_16x16x32_bf16(W2f[cur][nt], Pf[ii], acc2[ii][nt], 0, 0, 0);
    }
  }

  // ---- epilogue: bias + gate + resample + line-coalesced atomic accumulate
  // lane holds px = lr (16 consecutive), oc = nt*16 + l4 + j, conv row py = wid*2 + ii
  const size_t ob = (size_t)b*1048576;
  if (type == 0){
    #pragma unroll
    for (int ii = 0; ii < 2; ++ii){
      int gy = ty0 + wid*2 + ii;
      #pragma unroll
      for (int nt = 0; nt < 4; ++nt)
        #pragma unroll
        for (int j = 0; j < 4; ++j){
          int oc = nt*16 + l4 + j;
          atomicAdd(out + ob + (size_t)oc*16384 + gy*128 + tx0 + lr,
                    g*(acc2[ii][nt][j] + b2[e*64 + oc]));
        }
    }
  } else if (type == 1){
    // 2x2 maxpool: vertical pair in-register (ii 0/1), horizontal pair cross-lane
    int Py = (ty0 + wid*2) >> 1;
    int Px = (tx0 + lr) >> 1;
    #pragma unroll
    for (int nt = 0; nt < 4; ++nt)
      #pragma unroll
      for (int j = 0; j < 4; ++j){
        int oc = nt*16 + l4 + j;
        float v = fmaxf(acc2[0][nt][j], acc2[1][nt][j]);
        v = fmaxf(v, __shfl_xor(v, 1));
        if ((lane & 1) == 0)
          atomicAdd(out + ob + (size_t)oc*16384 + Py*128 + Px, g*(v + b2[e*64 + oc]));
      }
  } else {
    // nearest 2x upsample: each conv pixel -> 2x2 block at 128-res
    #pragma unroll
    for (int ii = 0; ii < 2; ++ii){
      int gy = (ty0 + wid*2 + ii)*2;
      #pragma unroll
      for (int nt = 0; nt < 4; ++nt)
        #pragma unroll
        for (int j = 0; j < 4; ++j){
          int oc = nt*16 + l4 + j;
          float v = g*(acc2[ii][nt][j] + b2[e*64 + oc]);
          float* o = out + ob + (size_t)oc*16384 + gy*128 + (tx0 + lr)*2;
          atomicAdd(o,       v); atomicAdd(o + 1,   v);
          atomicAdd(o + 128, v); atomicAdd(o + 129, v);
        }
    }
  }
}

extern "C" void kernel_launch(void* const* d_in, const int* in_sizes, int n_in,
                              void* d_out, int out_size, void* d_ws, size_t ws_size,
                              hipStream_t stream) {
  (void)in_sizes; (void)n_in; (void)ws_size;
  const float* x  = (const float*)d_in[0];
  const float* tf = (const float*)d_in[1];
  const float* Wx = (const float*)d_in[2];
  const float* Wt = (const float*)d_in[3];
  const float* bg = (const float*)d_in[4];
  const float* W1 = (const float*)d_in[5];
  const float* b1 = (const float*)d_in[6];
  const float* W2 = (const float*)d_in[7];
  const float* b2 = (const float*)d_in[8];
  float* out = (float*)d_out;
  unsigned short* wt = (unsigned short*)d_ws;
  float* wsf = (float*)d_ws;
  unsigned short* xtb = (unsigned short*)((char*)d_ws + XT_OFF_B);

  hipMemsetAsync(d_out, 0, (size_t)out_size*sizeof(float), stream);
  wtrans_kernel<<<4608, 256, 0, stream>>>(W1, W2, wt);
  xpose_pool_kernel<<<dim3(64, 16), 256, 0, stream>>>(x, xtb, wsf);
  pool_reduce_kernel<<<4, 256, 0, stream>>>(wsf);
  gate_kernel<<<1, 256, 0, stream>>>(tf, Wx, Wt, bg, wsf, out + 16777216);

  moe_kernel<<<dim3(1744, 16), 512, 0, stream>>>(xtb, wt, wsf, b1, b2, out);
}

// Round 17
// 348.146 us; speedup vs baseline: 1.4667x; 1.4667x over previous
//
#include <hip/hip_runtime.h>
#include <cstdint>
#include <cstddef>

typedef __bf16 bf16x8 __attribute__((ext_vector_type(8)));
typedef float f32x4 __attribute__((ext_vector_type(4)));

// ---------------- ws layout ----------------
// bytes [0, 2359296): wt bf16 [16][2][9][64(oc)][64(ic)]
// float offset 589824: xp [16][64]; 590848: gates [16][16]; 591104: pool partials [16][64][64]
// bytes [4MB, 4MB+33554432): xt bf16 [16][16384(pixel)][64(ch)]  (NHWC)
#define XP_OFF_F    589824
#define GATES_OFF_F 590848
#define PART_OFF_F  591104
#define XT_OFF_B    (4u<<20)

// LDS xs geometry: 8 chunks x 404 pixels x 8 ch (bf16). chunk stride 3232 ushorts.
#define XCH 3232

__device__ __forceinline__ float bf2f(unsigned short h){
  return __uint_as_float(((uint32_t)h)<<16);
}
__device__ __forceinline__ unsigned short f2bf(float f){
  uint32_t u = __float_as_uint(f);
  u = u + 0x7fffu + ((u>>16)&1u);   // RNE
  return (unsigned short)(u>>16);
}
__device__ __forceinline__ uint32_t pk_bf16(float lo, float hi){
  uint32_t r;
  asm("v_cvt_pk_bf16_f32 %0, %1, %2" : "=v"(r) : "v"(lo), "v"(hi));
  return r;
}
// fast exact-GELU: erf via A&S 7.1.26 (|eps|<=1.5e-7, far below bf16 rounding)
__device__ __forceinline__ float gelu_exact(float x){
  float s = x * 0.70710678118654752440f;
  float a = __builtin_fabsf(s);
  float t = __builtin_amdgcn_rcpf(__builtin_fmaf(0.3275911f, a, 1.0f));
  float p = __builtin_fmaf(1.061405429f, t, -1.453152027f);
  p = __builtin_fmaf(p, t, 1.421413741f);
  p = __builtin_fmaf(p, t, -0.284496736f);
  p = __builtin_fmaf(p, t, 0.254829592f);
  p = p * t;
  float e = __expf(-a*a);
  float erfa = __builtin_fmaf(-p, e, 1.0f);
  float erfv = (s < 0.f) ? -erfa : erfa;
  return 0.5f * x * (1.0f + erfv);
}

// ---------------- weight transpose+cast: W[e][oc][ic][3][3] -> wt[e][c][tap][oc][ic] bf16
__global__ __launch_bounds__(256) void wtrans_kernel(const float* __restrict__ W1,
                                                     const float* __restrict__ W2,
                                                     unsigned short* __restrict__ wt){
  int idx = blockIdx.x*256 + threadIdx.x;      // 0 .. 1,179,647
  int ic  = idx & 63;
  int oc  = (idx>>6) & 63;
  int tap = (idx>>12) % 9;
  int ec  = idx / 36864;                       // e*2 + c
  int e = ec >> 1, c = ec & 1;
  const float* src = c ? W2 : W1;
  wt[idx] = f2bf(src[((e*64 + oc)*64 + ic)*9 + tap]);
}

// ---------------- fused: x NCHW fp32 -> NHWC bf16  +  pool partial sums
__global__ __launch_bounds__(256) void xpose_pool_kernel(const float* __restrict__ x,
                                                         unsigned short* __restrict__ xt,
                                                         float* __restrict__ wsf){
  int b = blockIdx.y;
  int tid = threadIdx.x;
  int p = blockIdx.x*256 + tid;                // 0..16383
  const float* xb = x + (size_t)b*1048576;
  __shared__ float part[64][4];
  const int lane = tid & 63, wid = tid >> 6;
  unsigned short v[64];
  #pragma unroll
  for (int c = 0; c < 64; ++c){
    float f = xb[c*16384 + p];
    v[c] = f2bf(f);
    #pragma unroll
    for (int off = 32; off; off >>= 1) f += __shfl_down(f, off);
    if (lane == 0) part[c][wid] = f;
  }
  uint4* dst = reinterpret_cast<uint4*>(xt + (size_t)b*1048576 + (size_t)p*64);
  const uint4* src = reinterpret_cast<const uint4*>(v);
  #pragma unroll
  for (int i = 0; i < 8; ++i) dst[i] = src[i];
  __syncthreads();
  if (tid < 64)
    wsf[PART_OFF_F + (b*64 + blockIdx.x)*64 + tid] =
      part[tid][0] + part[tid][1] + part[tid][2] + part[tid][3];
}

// ---------------- deterministic partial reduce -> xp[b][c]
__global__ __launch_bounds__(256) void pool_reduce_kernel(float* __restrict__ wsf){
  int i = blockIdx.x*256 + threadIdx.x;        // 0..1023 = b*64 + c
  int b = i >> 6, c = i & 63;
  float s = 0.f;
  for (int cx = 0; cx < 64; ++cx)
    s += wsf[PART_OFF_F + (b*64 + cx)*64 + c];
  wsf[XP_OFF_F + i] = s * (1.0f/16384.0f);
}

// ---------------- gating: logits -> softmax -> top2 -> gates + aux
__global__ __launch_bounds__(256) void gate_kernel(const float* __restrict__ tf,
    const float* __restrict__ Wx, const float* __restrict__ Wt,
    const float* __restrict__ bg, float* __restrict__ wsf,
    float* __restrict__ out_aux){
  __shared__ float lg[16][16];
  __shared__ float gsh[16][16];
  int tid = threadIdx.x;
  int b = tid >> 4, e = tid & 15;
  const float* xp = wsf + XP_OFF_F;
  float acc = bg[e];
  for (int c = 0; c < 64;  ++c) acc += xp[b*64 + c] * Wx[c*16 + e];
  for (int d = 0; d < 512; ++d) acc += tf[b*512 + d] * Wt[d*16 + e];
  lg[b][e] = acc;
  __syncthreads();
  if (tid < 16) {
    int bb = tid;
    float m = -1e30f;
    for (int j = 0; j < 16; ++j) m = fmaxf(m, lg[bb][j]);
    float pr[16]; float s = 0.f;
    for (int j = 0; j < 16; ++j){ pr[j] = expf(lg[bb][j] - m); s += pr[j]; }
    float invs = 1.f/s;
    for (int j = 0; j < 16; ++j) pr[j] *= invs;
    int i1 = 0; float v1 = pr[0];
    for (int j = 1; j < 16; ++j) if (pr[j] > v1){ v1 = pr[j]; i1 = j; }
    float v2 = -1.f; int i2 = 0;
    for (int j = 0; j < 16; ++j) if (j != i1 && pr[j] > v2){ v2 = pr[j]; i2 = j; }
    float inv = 1.f/(v1 + v2);
    for (int j = 0; j < 16; ++j) gsh[bb][j] = 0.f;
    gsh[bb][i1] = v1*inv;
    gsh[bb][i2] = v2*inv;
    for (int j = 0; j < 16; ++j) wsf[GATES_OFF_F + bb*16 + j] = gsh[bb][j];
  }
  __syncthreads();
  if (tid == 0){
    float imp[16]; float mean = 0.f;
    for (int j = 0; j < 16; ++j){
      float t = 0.f;
      for (int bb = 0; bb < 16; ++bb) t += gsh[bb][j];
      imp[j] = t; mean += t;
    }
    mean *= (1.f/16.f);
    float m2 = 0.f;
    for (int j = 0; j < 16; ++j){ float d = imp[j] - mean; m2 += d*d; }
    float var = m2 * (1.f/16.f);
    out_aux[0] = var / (mean*mean + 1e-10f);
  }
}

// ---------------- merged MoE kernel (round-13 proven structure): 512 threads,
// swapped-operand MFMA, async weight DMA (slab j -> wbuf[j%3], issue 2 ahead,
// counted s_waitcnt vmcnt(1) + bare barrier per tap; never drain to 0 in-loop).
// Per sample, blockIdx.x layout:
//   [0,384):     TYPE0, e = 3*(i/64),          tile = i%64   (8x8 tiles, S=128)
//   [384,1664):  TYPE1, e = 3*((i-384)/256)+1, tile = (i-384)%256 (16x16, S=256)
//   [1664,1744): TYPE2, e = 3*((i-1664)/16)+2, tile = (i-1664)%16 (4x4, S=64)
// conv as tap-decomposed GEMM: D[oc][px] = mfma(A=W[oc][ic], B=P[px][ic]).
__global__ __launch_bounds__(512, 4) void moe_kernel(
    const unsigned short* __restrict__ xt, const unsigned short* __restrict__ wt,
    const float* __restrict__ wsf,
    const float* __restrict__ b1, const float* __restrict__ b2,
    float* __restrict__ out)
{
  __shared__ unsigned short xs[8*XCH];     // 51.7 KB: [chunk][404 px][8 ch]; halo, then h1
  __shared__ unsigned short wbuf[3][4096]; // 24 KB: 3 x [64 oc][64 ic] tap slabs
  const int b = blockIdx.y;
  const int i = blockIdx.x;
  int e, tile, type, S, TILES;
  if (i < 384)       { type = 0; e = 3*(i>>6);            tile = i & 63;        S = 128; TILES = 8;  }
  else if (i < 1664) { type = 1; e = 3*((i-384)>>8) + 1;  tile = (i-384) & 255; S = 256; TILES = 16; }
  else               { type = 2; e = 3*((i-1664)>>4) + 2; tile = (i-1664) & 15; S = 64;  TILES = 4;  }

  const float g = wsf[GATES_OFF_F + b*16 + e];
  if (g == 0.0f) return;                 // inactive expert for this sample

  const int ty0 = (tile / TILES)*16;
  const int tx0 = (tile % TILES)*16;
  const int tid  = threadIdx.x;
  const int lane = tid & 63;
  const int wid  = tid >> 6;           // 0..7
  const int lr   = lane & 15;
  const int k16  = lane >> 4;          // 0..3
  const int l4   = k16 * 4;            // C/D row sub-offset

  const unsigned short* wt1 = wt + (size_t)(e*2 + 0)*36864;
  const unsigned short* wt2 = wt + (size_t)(e*2 + 1)*36864;
  const unsigned short* xtb = xt + (size_t)b*1048576;   // [pixel][64]

  // ---- preload conv1 bias into registers (no stray vmem loads inside the
  //      conv loops: the vmcnt(1) protocol counts only weight DMAs)
  float b1v[4][4];
  #pragma unroll
  for (int nt = 0; nt < 4; ++nt){
    float4 v = *reinterpret_cast<const float4*>(b1 + e*64 + nt*16 + l4);
    b1v[nt][0] = v.x; b1v[nt][1] = v.y; b1v[nt][2] = v.z; b1v[nt][3] = v.w;
  }

  // ---- async weight DMA: slab j (8KB) -> wbuf[j%3]
  const int woc = tid >> 3, wch = tid & 7;
  const int wsc = wch ^ (woc & 7);
  auto dma_slab = [&](int j){
    if (j < 18){
      const unsigned short* gsrc =
        ((j < 9) ? (wt1 + j*4096) : (wt2 + (j-9)*4096)) + woc*64 + wsc*8;
      __builtin_amdgcn_global_load_lds(
          (const __attribute__((address_space(1))) void*)gsrc,
          (__attribute__((address_space(3))) void*)(&wbuf[j % 3][wid << 9]),
          16, 0, 0);
    }
  };
  const int wb0 = lr*64 + (((0*4+k16) ^ (lr&7))*8);
  const int wb1 = lr*64 + (((1*4+k16) ^ (lr&7))*8);

  dma_slab(0); dma_slab(1);    // in flight during xs staging

  // ---- stage 20x20x64 input halo -> xs[chunk][p][8]; 400 px, 1 per thread
  if (tid < 400){
    int p = tid;
    int hy = p/20, hx = p - hy*20;
    int sy = ty0 - 2 + hy, sx = tx0 - 2 + hx;      // conv-res coords
    bool valid = (sy >= 0) & (sy < S) & (sx < S) & (sx >= 0);
    if (!valid){
      uint4 z = make_uint4(0,0,0,0);
      #pragma unroll
      for (int c = 0; c < 8; ++c)
        *reinterpret_cast<uint4*>(&xs[c*XCH + p*8]) = z;
    } else if (type == 0){
      const uint4* src = reinterpret_cast<const uint4*>(xtb + ((size_t)(sy*128 + sx))*64);
      #pragma unroll
      for (int c = 0; c < 8; ++c)
        *reinterpret_cast<uint4*>(&xs[c*XCH + p*8]) = src[c];
    } else if (type == 1){
      const uint4* src = reinterpret_cast<const uint4*>(xtb + ((size_t)((sy>>1)*128 + (sx>>1)))*64);
      #pragma unroll
      for (int c = 0; c < 8; ++c)
        *reinterpret_cast<uint4*>(&xs[c*XCH + p*8]) = src[c];
    } else {
      // 2x2 maxpool on bf16 (exact: RNE is monotone)
      const uint4* q00 = reinterpret_cast<const uint4*>(xtb + ((size_t)(sy*256 + sx*2))*64);
      const uint4* q01 = q00 + 8;
      const uint4* q10 = q00 + 128*8;
      const uint4* q11 = q10 + 8;
      #pragma unroll
      for (int c = 0; c < 8; ++c){
        union { unsigned short u[8]; uint4 v; } a0,a1,a2,a3,o;
        a0.v = q00[c]; a1.v = q01[c]; a2.v = q10[c]; a3.v = q11[c];
        #pragma unroll
        for (int j = 0; j < 8; ++j){
          float m = fmaxf(fmaxf(bf2f(a0.u[j]), bf2f(a1.u[j])),
                          fmaxf(bf2f(a2.u[j]), bf2f(a3.u[j])));
          o.u[j] = f2bf(m);
        }
        *reinterpret_cast<uint4*>(&xs[c*XCH + p*8]) = o.v;
      }
    }
  }

  // conv1 B-frag pixel bases (halo coords): 24 frags of 16 over 324 h1 px (clamped)
  int pb1[3];
  #pragma unroll
  for (int ii = 0; ii < 3; ++ii){
    int q = (wid*3 + ii)*16 + lr;
    q = q > 323 ? 323 : q;
    pb1[ii] = ((q/18)*20 + (q%18))*8 + k16*XCH;    // +kf*4*XCH, +poff*8 as imm
  }

  asm volatile("s_waitcnt lgkmcnt(0) vmcnt(1)" ::: "memory");
  __builtin_amdgcn_s_barrier();

  // ---- conv1: 9 tap-phases; slab t resident, slab t+1 arriving, issue t+2
  f32x4 acc1[3][4];
  #pragma unroll
  for (int ii = 0; ii < 3; ++ii)
    #pragma unroll
    for (int nt = 0; nt < 4; ++nt)
      acc1[ii][nt] = (f32x4){0.f,0.f,0.f,0.f};

  #pragma unroll
  for (int t = 0; t < 9; ++t){
    dma_slab(t+2);
    const unsigned short* wb = &wbuf[t % 3][0];
    const int poff = ((t/3)*20 + (t%3))*8;
    #pragma unroll
    for (int kf = 0; kf < 2; ++kf){
      bf16x8 Wf[4], Pf[3];
      #pragma unroll
      for (int nt = 0; nt < 4; ++nt)
        Wf[nt] = *reinterpret_cast<const bf16x8*>(wb + (kf ? wb1 : wb0) + nt*1024);
      #pragma unroll
      for (int ii = 0; ii < 3; ++ii)
        Pf[ii] = *reinterpret_cast<const bf16x8*>(&xs[pb1[ii] + kf*4*XCH + poff]);
      #pragma unroll
      for (int ii = 0; ii < 3; ++ii)
        #pragma unroll
        for (int nt = 0; nt < 4; ++nt)
          acc1[ii][nt] = __builtin_amdgcn_mfma_f32_16x16x32_bf16(Wf[nt], Pf[ii], acc1[ii][nt], 0, 0, 0);
    }
    // counted wait: slab t+1 resident, newest DMA stays in flight across barrier
    asm volatile("s_waitcnt vmcnt(1)" ::: "memory");
    __builtin_amdgcn_s_barrier();
  }

  // ---- bias + GELU -> h1 in xs[chunk][q][8] (zero outside image: ref zero-pads h1)
  #pragma unroll
  for (int ii = 0; ii < 3; ++ii){
    int q = (wid*3 + ii)*16 + lr;
    if (q < 324){
      int qy = q/18, qx = q - qy*18;
      int gy = ty0 - 1 + qy, gx = tx0 - 1 + qx;
      bool in_img = (gy >= 0) & (gy < S) & (gx >= 0) & (gx < S);
      int hb = (l4 >> 3)*XCH + q*8 + (l4 & 4);     // + nt*2*XCH as imm
      #pragma unroll
      for (int nt = 0; nt < 4; ++nt){
        float v0 = in_img ? gelu_exact(acc1[ii][nt][0] + b1v[nt][0]) : 0.f;
        float v1 = in_img ? gelu_exact(acc1[ii][nt][1] + b1v[nt][1]) : 0.f;
        float v2 = in_img ? gelu_exact(acc1[ii][nt][2] + b1v[nt][2]) : 0.f;
        float v3 = in_img ? gelu_exact(acc1[ii][nt][3] + b1v[nt][3]) : 0.f;
        uint2 w;
        w.x = pk_bf16(v0, v1);
        w.y = pk_bf16(v2, v3);
        *reinterpret_cast<uint2*>(&xs[nt*2*XCH + hb]) = w;
      }
    }
  }

  // h1 writes drained; weight DMAs (vmcnt) keep flowing
  asm volatile("s_waitcnt lgkmcnt(0)" ::: "memory");
  __builtin_amdgcn_s_barrier();

  // conv2 B-frag pixel bases
  int pb2[2];
  #pragma unroll
  for (int ii = 0; ii < 2; ++ii)
    pb2[ii] = ((wid*2 + ii)*18 + lr)*8 + k16*XCH;

  // ---- conv2: 9 tap-phases (slabs 9..17), same DMA protocol
  f32x4 acc2[2][4];
  #pragma unroll
  for (int ii = 0; ii < 2; ++ii)
    #pragma unroll
    for (int nt = 0; nt < 4; ++nt)
      acc2[ii][nt] = (f32x4){0.f,0.f,0.f,0.f};

  #pragma unroll
  for (int t2 = 0; t2 < 9; ++t2){
    const int t = 9 + t2;
    dma_slab(t+2);
    const unsigned short* wb = &wbuf[t % 3][0];
    const int poff = ((t2/3)*18 + (t2%3))*8;
    #pragma unroll
    for (int kf = 0; kf < 2; ++kf){
      bf16x8 Wf[4], Pf[2];
      #pragma unroll
      for (int nt = 0; nt < 4; ++nt)
        Wf[nt] = *reinterpret_cast<const bf16x8*>(wb + (kf ? wb1 : wb0) + nt*1024);
      #pragma unroll
      for (int ii = 0; ii < 2; ++ii)
        Pf[ii] = *reinterpret_cast<const bf16x8*>(&xs[pb2[ii] + kf*4*XCH + poff]);
      #pragma unroll
      for (int ii = 0; ii < 2; ++ii)
        #pragma unroll
        for (int nt = 0; nt < 4; ++nt)
          acc2[ii][nt] = __builtin_amdgcn_mfma_f32_16x16x32_bf16(Wf[nt], Pf[ii], acc2[ii][nt], 0, 0, 0);
    }
    if (t2 < 8){
      asm volatile("s_waitcnt vmcnt(1)" ::: "memory");
      __builtin_amdgcn_s_barrier();
    }
  }

  // ---- epilogue: bias + gate + resample + line-coalesced atomic accumulate
  // lane holds px = lr (16 consecutive), oc = nt*16 + l4 + j, conv row py = wid*2 + ii
  const size_t ob = (size_t)b*1048576;
  if (type == 0){
    #pragma unroll
    for (int ii = 0; ii < 2; ++ii){
      int gy = ty0 + wid*2 + ii;
      #pragma unroll
      for (int nt = 0; nt < 4; ++nt)
        #pragma unroll
        for (int j = 0; j < 4; ++j){
          int oc = nt*16 + l4 + j;
          atomicAdd(out + ob + (size_t)oc*16384 + gy*128 + tx0 + lr,
                    g*(acc2[ii][nt][j] + b2[e*64 + oc]));
        }
    }
  } else if (type == 1){
    // 2x2 maxpool: vertical pair in-register (ii 0/1), horizontal pair cross-lane
    int Py = (ty0 + wid*2) >> 1;
    int Px = (tx0 + lr) >> 1;
    #pragma unroll
    for (int nt = 0; nt < 4; ++nt)
      #pragma unroll
      for (int j = 0; j < 4; ++j){
        int oc = nt*16 + l4 + j;
        float v = fmaxf(acc2[0][nt][j], acc2[1][nt][j]);
        v = fmaxf(v, __shfl_xor(v, 1));
        if ((lane & 1) == 0)
          atomicAdd(out + ob + (size_t)oc*16384 + Py*128 + Px, g*(v + b2[e*64 + oc]));
      }
  } else {
    // nearest 2x upsample: each conv pixel -> 2x2 block at 128-res
    #pragma unroll
    for (int ii = 0; ii < 2; ++ii){
      int gy = (ty0 + wid*2 + ii)*2;
      #pragma unroll
      for (int nt = 0; nt < 4; ++nt)
        #pragma unroll
        for (int j = 0; j < 4; ++j){
          int oc = nt*16 + l4 + j;
          float v = g*(acc2[ii][nt][j] + b2[e*64 + oc]);
          float* o = out + ob + (size_t)oc*16384 + gy*128 + (tx0 + lr)*2;
          atomicAdd(o,       v); atomicAdd(o + 1,   v);
          atomicAdd(o + 128, v); atomicAdd(o + 129, v);
        }
    }
  }
}

extern "C" void kernel_launch(void* const* d_in, const int* in_sizes, int n_in,
                              void* d_out, int out_size, void* d_ws, size_t ws_size,
                              hipStream_t stream) {
  (void)in_sizes; (void)n_in; (void)ws_size;
  const float* x  = (const float*)d_in[0];
  const float* tf = (const float*)d_in[1];
  const float* Wx = (const float*)d_in[2];
  const float* Wt = (const float*)d_in[3];
  const float* bg = (const float*)d_in[4];
  const float* W1 = (const float*)d_in[5];
  const float* b1 = (const float*)d_in[6];
  const float* W2 = (const float*)d_in[7];
  const float* b2 = (const float*)d_in[8];
  float* out = (float*)d_out;
  unsigned short* wt = (unsigned short*)d_ws;
  float* wsf = (float*)d_ws;
  unsigned short* xtb = (unsigned short*)((char*)d_ws + XT_OFF_B);

  hipMemsetAsync(d_out, 0, (size_t)out_size*sizeof(float), stream);
  wtrans_kernel<<<4608, 256, 0, stream>>>(W1, W2, wt);
  xpose_pool_kernel<<<dim3(64, 16), 256, 0, stream>>>(x, xtb, wsf);
  pool_reduce_kernel<<<4, 256, 0, stream>>>(wsf);
  gate_kernel<<<1, 256, 0, stream>>>(tf, Wx, Wt, bg, wsf, out + 16777216);

  moe_kernel<<<dim3(1744, 16), 512, 0, stream>>>(xtb, wt, wsf, b1, b2, out);
}

// Round 18
// 344.856 us; speedup vs baseline: 1.4807x; 1.0095x over previous
//
#include <hip/hip_runtime.h>
#include <cstdint>
#include <cstddef>

typedef __bf16 bf16x8 __attribute__((ext_vector_type(8)));
typedef float f32x4 __attribute__((ext_vector_type(4)));

// ---------------- ws layout ----------------
// bytes [0, 2359296): wt bf16 [16][2][9][64(oc)][64(ic)]
// float offset 590848: gates [16][16]; 591104: pool partials [16][64][64]
// bytes [4MB, 4MB+33554432): xt bf16 [16][16384(pixel)][64(ch)]  (NHWC)
#define GATES_OFF_F 590848
#define PART_OFF_F  591104
#define XT_OFF_B    (4u<<20)

// LDS xs geometry: 8 chunks x 404 pixels x 8 ch (bf16). chunk stride 3232 ushorts.
#define XCH 3232

__device__ __forceinline__ float bf2f(unsigned short h){
  return __uint_as_float(((uint32_t)h)<<16);
}
__device__ __forceinline__ unsigned short f2bf(float f){
  uint32_t u = __float_as_uint(f);
  u = u + 0x7fffu + ((u>>16)&1u);   // RNE
  return (unsigned short)(u>>16);
}
__device__ __forceinline__ uint32_t pk_bf16(float lo, float hi){
  uint32_t r;
  asm("v_cvt_pk_bf16_f32 %0, %1, %2" : "=v"(r) : "v"(lo), "v"(hi));
  return r;
}
// fast exact-GELU: erf via A&S 7.1.26 (|eps|<=1.5e-7, far below bf16 rounding)
__device__ __forceinline__ float gelu_exact(float x){
  float s = x * 0.70710678118654752440f;
  float a = __builtin_fabsf(s);
  float t = __builtin_amdgcn_rcpf(__builtin_fmaf(0.3275911f, a, 1.0f));
  float p = __builtin_fmaf(1.061405429f, t, -1.453152027f);
  p = __builtin_fmaf(p, t, 1.421413741f);
  p = __builtin_fmaf(p, t, -0.284496736f);
  p = __builtin_fmaf(p, t, 0.254829592f);
  p = p * t;
  float e = __expf(-a*a);
  float erfa = __builtin_fmaf(-p, e, 1.0f);
  float erfv = (s < 0.f) ? -erfa : erfa;
  return 0.5f * x * (1.0f + erfv);
}

// ---------------- merged prep: xpose+pool (blocks 0..1023) | wtrans (1024..5631)
__global__ __launch_bounds__(256) void prep_kernel(const float* __restrict__ x,
                                                   const float* __restrict__ W1,
                                                   const float* __restrict__ W2,
                                                   unsigned short* __restrict__ xt,
                                                   unsigned short* __restrict__ wt,
                                                   float* __restrict__ wsf){
  __shared__ float part[64][4];
  const int blk = blockIdx.x;
  const int tid = threadIdx.x;
  if (blk < 1024){
    // x NCHW fp32 -> NHWC bf16 + pool partial sums
    int b = blk >> 6;
    int p = (blk & 63)*256 + tid;              // 0..16383
    const float* xb = x + (size_t)b*1048576;
    const int lane = tid & 63, wid = tid >> 6;
    unsigned short v[64];
    #pragma unroll
    for (int c = 0; c < 64; ++c){
      float f = xb[c*16384 + p];
      v[c] = f2bf(f);
      #pragma unroll
      for (int off = 32; off; off >>= 1) f += __shfl_down(f, off);
      if (lane == 0) part[c][wid] = f;
    }
    uint4* dst = reinterpret_cast<uint4*>(xt + (size_t)b*1048576 + (size_t)p*64);
    const uint4* src = reinterpret_cast<const uint4*>(v);
    #pragma unroll
    for (int i = 0; i < 8; ++i) dst[i] = src[i];
    __syncthreads();
    if (tid < 64)
      wsf[PART_OFF_F + (b*64 + (blk & 63))*64 + tid] =
        part[tid][0] + part[tid][1] + part[tid][2] + part[tid][3];
  } else {
    // weight transpose+cast: W[e][oc][ic][3][3] -> wt[e][c][tap][oc][ic] bf16
    int idx = (blk - 1024)*256 + tid;          // 0 .. 1,179,647
    int ic  = idx & 63;
    int oc  = (idx>>6) & 63;
    int tap = (idx>>12) % 9;
    int ec  = idx / 36864;                     // e*2 + c
    int e = ec >> 1, c = ec & 1;
    const float* src = c ? W2 : W1;
    wt[idx] = f2bf(src[((e*64 + oc)*64 + ic)*9 + tap]);
  }
}

// ---------------- merged gate: partial reduce -> xp (LDS) -> softmax top2 + aux
__global__ __launch_bounds__(256) void gate2_kernel(const float* __restrict__ tf,
    const float* __restrict__ Wx, const float* __restrict__ Wt,
    const float* __restrict__ bg, float* __restrict__ wsf,
    float* __restrict__ out_aux){
  __shared__ float xpl[16][64];
  __shared__ float lg[16][16];
  __shared__ float gsh[16][16];
  int tid = threadIdx.x;
  // phase 1: deterministic reduce of pool partials -> xp in LDS
  #pragma unroll
  for (int k = 0; k < 4; ++k){
    int i = k*256 + tid;                       // 0..1023 = b*64 + c
    int b = i >> 6, c = i & 63;
    float s = 0.f;
    for (int cx = 0; cx < 64; ++cx)
      s += wsf[PART_OFF_F + (b*64 + cx)*64 + c];
    xpl[b][c] = s * (1.0f/16384.0f);
  }
  __syncthreads();
  // phase 2: logits
  int b = tid >> 4, e = tid & 15;
  float acc = bg[e];
  for (int c = 0; c < 64;  ++c) acc += xpl[b][c] * Wx[c*16 + e];
  for (int d = 0; d < 512; ++d) acc += tf[b*512 + d] * Wt[d*16 + e];
  lg[b][e] = acc;
  __syncthreads();
  if (tid < 16) {
    int bb = tid;
    float m = -1e30f;
    for (int j = 0; j < 16; ++j) m = fmaxf(m, lg[bb][j]);
    float pr[16]; float s = 0.f;
    for (int j = 0; j < 16; ++j){ pr[j] = expf(lg[bb][j] - m); s += pr[j]; }
    float invs = 1.f/s;
    for (int j = 0; j < 16; ++j) pr[j] *= invs;
    int i1 = 0; float v1 = pr[0];
    for (int j = 1; j < 16; ++j) if (pr[j] > v1){ v1 = pr[j]; i1 = j; }
    float v2 = -1.f; int i2 = 0;
    for (int j = 0; j < 16; ++j) if (j != i1 && pr[j] > v2){ v2 = pr[j]; i2 = j; }
    float inv = 1.f/(v1 + v2);
    for (int j = 0; j < 16; ++j) gsh[bb][j] = 0.f;
    gsh[bb][i1] = v1*inv;
    gsh[bb][i2] = v2*inv;
    for (int j = 0; j < 16; ++j) wsf[GATES_OFF_F + bb*16 + j] = gsh[bb][j];
  }
  __syncthreads();
  if (tid == 0){
    float imp[16]; float mean = 0.f;
    for (int j = 0; j < 16; ++j){
      float t = 0.f;
      for (int bb = 0; bb < 16; ++bb) t += gsh[bb][j];
      imp[j] = t; mean += t;
    }
    mean *= (1.f/16.f);
    float m2 = 0.f;
    for (int j = 0; j < 16; ++j){ float d = imp[j] - mean; m2 += d*d; }
    float var = m2 * (1.f/16.f);
    out_aux[0] = var / (mean*mean + 1e-10f);
  }
}

// ---------------- merged MoE kernel (round-13 proven structure): 512 threads,
// swapped-operand MFMA, async weight DMA (slab j -> wbuf[j%3], issue 2 ahead,
// counted s_waitcnt vmcnt(1) + bare barrier per tap; never drain to 0 in-loop).
// Per sample, blockIdx.x layout:
//   [0,384):     TYPE0, e = 3*(i/64),          tile = i%64   (8x8 tiles, S=128)
//   [384,1664):  TYPE1, e = 3*((i-384)/256)+1, tile = (i-384)%256 (16x16, S=256)
//   [1664,1744): TYPE2, e = 3*((i-1664)/16)+2, tile = (i-1664)%16 (4x4, S=64)
// conv as tap-decomposed GEMM: D[oc][px] = mfma(A=W[oc][ic], B=P[px][ic]).
__global__ __launch_bounds__(512, 4) void moe_kernel(
    const unsigned short* __restrict__ xt, const unsigned short* __restrict__ wt,
    const float* __restrict__ wsf,
    const float* __restrict__ b1, const float* __restrict__ b2,
    float* __restrict__ out)
{
  __shared__ unsigned short xs[8*XCH];     // 51.7 KB: [chunk][404 px][8 ch]; halo, then h1
  __shared__ unsigned short wbuf[3][4096]; // 24 KB: 3 x [64 oc][64 ic] tap slabs
  const int b = blockIdx.y;
  const int i = blockIdx.x;
  int e, tile, type, S, TILES;
  if (i < 384)       { type = 0; e = 3*(i>>6);            tile = i & 63;        S = 128; TILES = 8;  }
  else if (i < 1664) { type = 1; e = 3*((i-384)>>8) + 1;  tile = (i-384) & 255; S = 256; TILES = 16; }
  else               { type = 2; e = 3*((i-1664)>>4) + 2; tile = (i-1664) & 15; S = 64;  TILES = 4;  }

  const float g = wsf[GATES_OFF_F + b*16 + e];
  if (g == 0.0f) return;                 // inactive expert for this sample

  const int ty0 = (tile / TILES)*16;
  const int tx0 = (tile % TILES)*16;
  const int tid  = threadIdx.x;
  const int lane = tid & 63;
  const int wid  = tid >> 6;           // 0..7
  const int lr   = lane & 15;
  const int k16  = lane >> 4;          // 0..3
  const int l4   = k16 * 4;            // C/D row sub-offset

  const unsigned short* wt1 = wt + (size_t)(e*2 + 0)*36864;
  const unsigned short* wt2 = wt + (size_t)(e*2 + 1)*36864;
  const unsigned short* xtb = xt + (size_t)b*1048576;   // [pixel][64]

  // ---- preload conv1 bias into registers (no stray vmem loads inside the
  //      conv loops: the vmcnt(1) protocol counts only weight DMAs)
  float b1v[4][4];
  #pragma unroll
  for (int nt = 0; nt < 4; ++nt){
    float4 v = *reinterpret_cast<const float4*>(b1 + e*64 + nt*16 + l4);
    b1v[nt][0] = v.x; b1v[nt][1] = v.y; b1v[nt][2] = v.z; b1v[nt][3] = v.w;
  }

  // ---- async weight DMA: slab j (8KB) -> wbuf[j%3]
  const int woc = tid >> 3, wch = tid & 7;
  const int wsc = wch ^ (woc & 7);
  auto dma_slab = [&](int j){
    if (j < 18){
      const unsigned short* gsrc =
        ((j < 9) ? (wt1 + j*4096) : (wt2 + (j-9)*4096)) + woc*64 + wsc*8;
      __builtin_amdgcn_global_load_lds(
          (const __attribute__((address_space(1))) void*)gsrc,
          (__attribute__((address_space(3))) void*)(&wbuf[j % 3][wid << 9]),
          16, 0, 0);
    }
  };
  const int wb0 = lr*64 + (((0*4+k16) ^ (lr&7))*8);
  const int wb1 = lr*64 + (((1*4+k16) ^ (lr&7))*8);

  dma_slab(0); dma_slab(1);    // in flight during xs staging

  // ---- stage 20x20x64 input halo -> xs[chunk][p][8]; 400 px, 1 per thread
  if (tid < 400){
    int p = tid;
    int hy = p/20, hx = p - hy*20;
    int sy = ty0 - 2 + hy, sx = tx0 - 2 + hx;      // conv-res coords
    bool valid = (sy >= 0) & (sy < S) & (sx < S) & (sx >= 0);
    if (!valid){
      uint4 z = make_uint4(0,0,0,0);
      #pragma unroll
      for (int c = 0; c < 8; ++c)
        *reinterpret_cast<uint4*>(&xs[c*XCH + p*8]) = z;
    } else if (type == 0){
      const uint4* src = reinterpret_cast<const uint4*>(xtb + ((size_t)(sy*128 + sx))*64);
      #pragma unroll
      for (int c = 0; c < 8; ++c)
        *reinterpret_cast<uint4*>(&xs[c*XCH + p*8]) = src[c];
    } else if (type == 1){
      const uint4* src = reinterpret_cast<const uint4*>(xtb + ((size_t)((sy>>1)*128 + (sx>>1)))*64);
      #pragma unroll
      for (int c = 0; c < 8; ++c)
        *reinterpret_cast<uint4*>(&xs[c*XCH + p*8]) = src[c];
    } else {
      // 2x2 maxpool on bf16 (exact: RNE is monotone)
      const uint4* q00 = reinterpret_cast<const uint4*>(xtb + ((size_t)(sy*256 + sx*2))*64);
      const uint4* q01 = q00 + 8;
      const uint4* q10 = q00 + 128*8;
      const uint4* q11 = q10 + 8;
      #pragma unroll
      for (int c = 0; c < 8; ++c){
        union { unsigned short u[8]; uint4 v; } a0,a1,a2,a3,o;
        a0.v = q00[c]; a1.v = q01[c]; a2.v = q10[c]; a3.v = q11[c];
        #pragma unroll
        for (int j = 0; j < 8; ++j){
          float m = fmaxf(fmaxf(bf2f(a0.u[j]), bf2f(a1.u[j])),
                          fmaxf(bf2f(a2.u[j]), bf2f(a3.u[j])));
          o.u[j] = f2bf(m);
        }
        *reinterpret_cast<uint4*>(&xs[c*XCH + p*8]) = o.v;
      }
    }
  }

  // conv1 B-frag pixel bases (halo coords): 24 frags of 16 over 324 h1 px (clamped)
  int pb1[3];
  #pragma unroll
  for (int ii = 0; ii < 3; ++ii){
    int q = (wid*3 + ii)*16 + lr;
    q = q > 323 ? 323 : q;
    pb1[ii] = ((q/18)*20 + (q%18))*8 + k16*XCH;    // +kf*4*XCH, +poff*8 as imm
  }

  asm volatile("s_waitcnt lgkmcnt(0) vmcnt(1)" ::: "memory");
  __builtin_amdgcn_s_barrier();

  // ---- conv1: 9 tap-phases; slab t resident, slab t+1 arriving, issue t+2
  f32x4 acc1[3][4];
  #pragma unroll
  for (int ii = 0; ii < 3; ++ii)
    #pragma unroll
    for (int nt = 0; nt < 4; ++nt)
      acc1[ii][nt] = (f32x4){0.f,0.f,0.f,0.f};

  #pragma unroll
  for (int t = 0; t < 9; ++t){
    dma_slab(t+2);
    const unsigned short* wb = &wbuf[t % 3][0];
    const int poff = ((t/3)*20 + (t%3))*8;
    #pragma unroll
    for (int kf = 0; kf < 2; ++kf){
      bf16x8 Wf[4], Pf[3];
      #pragma unroll
      for (int nt = 0; nt < 4; ++nt)
        Wf[nt] = *reinterpret_cast<const bf16x8*>(wb + (kf ? wb1 : wb0) + nt*1024);
      #pragma unroll
      for (int ii = 0; ii < 3; ++ii)
        Pf[ii] = *reinterpret_cast<const bf16x8*>(&xs[pb1[ii] + kf*4*XCH + poff]);
      #pragma unroll
      for (int ii = 0; ii < 3; ++ii)
        #pragma unroll
        for (int nt = 0; nt < 4; ++nt)
          acc1[ii][nt] = __builtin_amdgcn_mfma_f32_16x16x32_bf16(Wf[nt], Pf[ii], acc1[ii][nt], 0, 0, 0);
    }
    // counted wait: slab t+1 resident, newest DMA stays in flight across barrier
    asm volatile("s_waitcnt vmcnt(1)" ::: "memory");
    __builtin_amdgcn_s_barrier();
  }

  // ---- bias + GELU -> h1 in xs[chunk][q][8] (zero outside image: ref zero-pads h1)
  #pragma unroll
  for (int ii = 0; ii < 3; ++ii){
    int q = (wid*3 + ii)*16 + lr;
    if (q < 324){
      int qy = q/18, qx = q - qy*18;
      int gy = ty0 - 1 + qy, gx = tx0 - 1 + qx;
      bool in_img = (gy >= 0) & (gy < S) & (gx >= 0) & (gx < S);
      int hb = (l4 >> 3)*XCH + q*8 + (l4 & 4);     // + nt*2*XCH as imm
      #pragma unroll
      for (int nt = 0; nt < 4; ++nt){
        float v0 = in_img ? gelu_exact(acc1[ii][nt][0] + b1v[nt][0]) : 0.f;
        float v1 = in_img ? gelu_exact(acc1[ii][nt][1] + b1v[nt][1]) : 0.f;
        float v2 = in_img ? gelu_exact(acc1[ii][nt][2] + b1v[nt][2]) : 0.f;
        float v3 = in_img ? gelu_exact(acc1[ii][nt][3] + b1v[nt][3]) : 0.f;
        uint2 w;
        w.x = pk_bf16(v0, v1);
        w.y = pk_bf16(v2, v3);
        *reinterpret_cast<uint2*>(&xs[nt*2*XCH + hb]) = w;
      }
    }
  }

  // h1 writes drained; weight DMAs (vmcnt) keep flowing
  asm volatile("s_waitcnt lgkmcnt(0)" ::: "memory");
  __builtin_amdgcn_s_barrier();

  // conv2 B-frag pixel bases
  int pb2[2];
  #pragma unroll
  for (int ii = 0; ii < 2; ++ii)
    pb2[ii] = ((wid*2 + ii)*18 + lr)*8 + k16*XCH;

  // ---- conv2: 9 tap-phases (slabs 9..17), same DMA protocol
  f32x4 acc2[2][4];
  #pragma unroll
  for (int ii = 0; ii < 2; ++ii)
    #pragma unroll
    for (int nt = 0; nt < 4; ++nt)
      acc2[ii][nt] = (f32x4){0.f,0.f,0.f,0.f};

  #pragma unroll
  for (int t2 = 0; t2 < 9; ++t2){
    const int t = 9 + t2;
    dma_slab(t+2);
    const unsigned short* wb = &wbuf[t % 3][0];
    const int poff = ((t2/3)*18 + (t2%3))*8;
    #pragma unroll
    for (int kf = 0; kf < 2; ++kf){
      bf16x8 Wf[4], Pf[2];
      #pragma unroll
      for (int nt = 0; nt < 4; ++nt)
        Wf[nt] = *reinterpret_cast<const bf16x8*>(wb + (kf ? wb1 : wb0) + nt*1024);
      #pragma unroll
      for (int ii = 0; ii < 2; ++ii)
        Pf[ii] = *reinterpret_cast<const bf16x8*>(&xs[pb2[ii] + kf*4*XCH + poff]);
      #pragma unroll
      for (int ii = 0; ii < 2; ++ii)
        #pragma unroll
        for (int nt = 0; nt < 4; ++nt)
          acc2[ii][nt] = __builtin_amdgcn_mfma_f32_16x16x32_bf16(Wf[nt], Pf[ii], acc2[ii][nt], 0, 0, 0);
    }
    if (t2 < 8){
      asm volatile("s_waitcnt vmcnt(1)" ::: "memory");
      __builtin_amdgcn_s_barrier();
    }
  }

  // ---- epilogue: bias + gate + resample + line-coalesced atomic accumulate
  // lane holds px = lr (16 consecutive), oc = nt*16 + l4 + j, conv row py = wid*2 + ii
  const size_t ob = (size_t)b*1048576;
  if (type == 0){
    #pragma unroll
    for (int ii = 0; ii < 2; ++ii){
      int gy = ty0 + wid*2 + ii;
      #pragma unroll
      for (int nt = 0; nt < 4; ++nt)
        #pragma unroll
        for (int j = 0; j < 4; ++j){
          int oc = nt*16 + l4 + j;
          atomicAdd(out + ob + (size_t)oc*16384 + gy*128 + tx0 + lr,
                    g*(acc2[ii][nt][j] + b2[e*64 + oc]));
        }
    }
  } else if (type == 1){
    // 2x2 maxpool: vertical pair in-register (ii 0/1), horizontal pair cross-lane
    int Py = (ty0 + wid*2) >> 1;
    int Px = (tx0 + lr) >> 1;
    #pragma unroll
    for (int nt = 0; nt < 4; ++nt)
      #pragma unroll
      for (int j = 0; j < 4; ++j){
        int oc = nt*16 + l4 + j;
        float v = fmaxf(acc2[0][nt][j], acc2[1][nt][j]);
        v = fmaxf(v, __shfl_xor(v, 1));
        if ((lane & 1) == 0)
          atomicAdd(out + ob + (size_t)oc*16384 + Py*128 + Px, g*(v + b2[e*64 + oc]));
      }
  } else {
    // nearest 2x upsample: each conv pixel -> 2x2 block at 128-res
    #pragma unroll
    for (int ii = 0; ii < 2; ++ii){
      int gy = (ty0 + wid*2 + ii)*2;
      #pragma unroll
      for (int nt = 0; nt < 4; ++nt)
        #pragma unroll
        for (int j = 0; j < 4; ++j){
          int oc = nt*16 + l4 + j;
          float v = g*(acc2[ii][nt][j] + b2[e*64 + oc]);
          float* o = out + ob + (size_t)oc*16384 + gy*128 + (tx0 + lr)*2;
          atomicAdd(o,       v); atomicAdd(o + 1,   v);
          atomicAdd(o + 128, v); atomicAdd(o + 129, v);
        }
    }
  }
}

extern "C" void kernel_launch(void* const* d_in, const int* in_sizes, int n_in,
                              void* d_out, int out_size, void* d_ws, size_t ws_size,
                              hipStream_t stream) {
  (void)in_sizes; (void)n_in; (void)ws_size;
  const float* x  = (const float*)d_in[0];
  const float* tf = (const float*)d_in[1];
  const float* Wx = (const float*)d_in[2];
  const float* Wt = (const float*)d_in[3];
  const float* bg = (const float*)d_in[4];
  const float* W1 = (const float*)d_in[5];
  const float* b1 = (const float*)d_in[6];
  const float* W2 = (const float*)d_in[7];
  const float* b2 = (const float*)d_in[8];
  float* out = (float*)d_out;
  unsigned short* wt = (unsigned short*)d_ws;
  float* wsf = (float*)d_ws;
  unsigned short* xtb = (unsigned short*)((char*)d_ws + XT_OFF_B);

  hipMemsetAsync(d_out, 0, (size_t)out_size*sizeof(float), stream);
  prep_kernel<<<5632, 256, 0, stream>>>(x, W1, W2, xtb, wt, wsf);
  gate2_kernel<<<1, 256, 0, stream>>>(tf, Wx, Wt, bg, wsf, out + 16777216);

  moe_kernel<<<dim3(1744, 16), 512, 0, stream>>>(xtb, wt, wsf, b1, b2, out);
}